// Round 1
// baseline (552.959 us; speedup 1.0000x reference)
//
#include <hip/hip_runtime.h>
#include <hip/hip_bf16.h>
#include <stdint.h>

#define T_DIM 512
#define IN_DIM 4096
#define OUT_DIM 11008

typedef __attribute__((ext_vector_type(8))) __bf16 bf16x8;
typedef __attribute__((ext_vector_type(8))) short shortx8;
typedef __attribute__((ext_vector_type(4))) float f32x4;

__device__ __forceinline__ short f32_to_bf16_bits(float f) {
    uint32_t x = __builtin_bit_cast(uint32_t, f);
    x += 0x7FFFu + ((x >> 16) & 1u);   // RTNE; inputs are finite
    return (short)(x >> 16);
}

// ---- quantize activations: xq = sf_decode(sf_encode(x)), stored as bf16 ----
__global__ __launch_bounds__(256) void encode_x_kernel(const float* __restrict__ x,
                                                       short* __restrict__ xq) {
    const float MAXV = 2047.0f / 2048.0f;
    int i = (blockIdx.x * 256 + threadIdx.x) * 8;
    float4 a = *(const float4*)(x + i);
    float4 b = *(const float4*)(x + i + 4);
    float v[8] = {a.x, a.y, a.z, a.w, b.x, b.y, b.z, b.w};
    union { short s[8]; int4 v4; } u;
#pragma unroll
    for (int j = 0; j < 8; ++j) {
        float xv = v[j];
        float ax = fminf(fabsf(xv), MAXV);
        float m = floorf(ax * 2047.0f / MAXV);   // faithful two-step rounding
        // reference sign convention: (2*sign-1) -> +1 when x<0, -1 otherwise
        float q = m * (1.0f / 2048.0f) * (xv < 0.0f ? 1.0f : -1.0f);
        u.s[j] = f32_to_bf16_bits(q);
    }
    *(int4*)(xq + i) = u.v4;
}

// ---- decode weights: sf_decode(enc), outlier scatter, per-row scale -> bf16 ----
__global__ __launch_bounds__(256) void decode_w_kernel(const int* __restrict__ enc,
                                                       const int* __restrict__ mask,
                                                       const float* __restrict__ wf,
                                                       const float* __restrict__ scale,
                                                       short* __restrict__ wq) {
    int i = (blockIdx.x * 256 + threadIdx.x) * 8;
    int row = i >> 12;                    // / IN_DIM
    float s = scale[row];
    int4 e0 = *(const int4*)(enc + i);
    int4 e1 = *(const int4*)(enc + i + 4);
    int4 m0 = *(const int4*)(mask + i);
    int4 m1 = *(const int4*)(mask + i + 4);
    int e[8]  = {e0.x, e0.y, e0.z, e0.w, e1.x, e1.y, e1.z, e1.w};
    int mk[8] = {m0.x, m0.y, m0.z, m0.w, m1.x, m1.y, m1.z, m1.w};
    union { short s[8]; int4 v4; } u;
#pragma unroll
    for (int j = 0; j < 8; ++j) {
        int ev = e[j];
        // sf_decode: mantissa/2048, sign bit set -> +1, clear -> -1 (faithful)
        float v = (float)(ev & 2047) * (1.0f / 2048.0f) * (((ev >> 11) & 1) ? 1.0f : -1.0f);
        if (mk[j]) v = wf[i + j];         // exec-masked load: ~8% of lines touched
        u.s[j] = f32_to_bf16_bits(v * s);
    }
    *(int4*)(wq + i) = u.v4;
}

// ---- C[512,11008] = A[512,4096] @ B[11008,4096]^T + bias, bf16 MFMA ----
#define BM 128
#define BN 128
#define BK 32
#define KITERS (IN_DIM / BK)

__global__ __launch_bounds__(256) void gemm_bt_kernel(const short* __restrict__ A,
                                                      const short* __restrict__ B,
                                                      const float* __restrict__ bias,
                                                      float* __restrict__ C) {
    __shared__ short As[BM * BK];   // 8 KB
    __shared__ short Bs[BN * BK];   // 8 KB
    const int tid  = threadIdx.x;
    const int wave = tid >> 6;
    const int lane = tid & 63;
    const int bn = blockIdx.x, bm = blockIdx.y;

    // staging: flat bf16 element f = (it*256 + tid)*8 within [128][32] tile
    const int f0 = tid * 8;
    const int r0 = f0 >> 5, c0 = f0 & 31;
    const int f1 = (256 + tid) * 8;
    const int r1 = f1 >> 5, c1 = f1 & 31;
    const short* gA0 = A + (size_t)(bm * BM + r0) * IN_DIM + c0;
    const short* gA1 = A + (size_t)(bm * BM + r1) * IN_DIM + c1;
    const short* gB0 = B + (size_t)(bn * BN + r0) * IN_DIM + c0;
    const short* gB1 = B + (size_t)(bn * BN + r1) * IN_DIM + c1;
    // wave-uniform LDS bases: lane's 16B lands at base + lane*16
    short* lA0 = As + (wave * 64) * 8;
    short* lA1 = As + (256 + wave * 64) * 8;
    short* lB0 = Bs + (wave * 64) * 8;
    short* lB1 = Bs + (256 + wave * 64) * 8;

    const int wm = (wave >> 1) * 64;
    const int wn = (wave & 1) * 64;
    const int quad = lane >> 4;
    const int lr   = lane & 15;

    f32x4 acc[4][4] = {};

    for (int kt = 0; kt < KITERS; ++kt) {
        const int ko = kt * BK;
        __builtin_amdgcn_global_load_lds((__attribute__((address_space(1))) void*)(gA0 + ko),
                                         (__attribute__((address_space(3))) void*)lA0, 16, 0, 0);
        __builtin_amdgcn_global_load_lds((__attribute__((address_space(1))) void*)(gA1 + ko),
                                         (__attribute__((address_space(3))) void*)lA1, 16, 0, 0);
        __builtin_amdgcn_global_load_lds((__attribute__((address_space(1))) void*)(gB0 + ko),
                                         (__attribute__((address_space(3))) void*)lB0, 16, 0, 0);
        __builtin_amdgcn_global_load_lds((__attribute__((address_space(1))) void*)(gB1 + ko),
                                         (__attribute__((address_space(3))) void*)lB1, 16, 0, 0);
        __syncthreads();   // drains vmcnt(0): tile visible

        bf16x8 af[4], bfr[4];
#pragma unroll
        for (int mi = 0; mi < 4; ++mi)
            af[mi] = __builtin_bit_cast(bf16x8,
                *(const shortx8*)(As + (wm + mi * 16 + lr) * BK + quad * 8));
#pragma unroll
        for (int ni = 0; ni < 4; ++ni)
            bfr[ni] = __builtin_bit_cast(bf16x8,
                *(const shortx8*)(Bs + (wn + ni * 16 + lr) * BK + quad * 8));
#pragma unroll
        for (int mi = 0; mi < 4; ++mi)
#pragma unroll
            for (int ni = 0; ni < 4; ++ni)
                acc[mi][ni] = __builtin_amdgcn_mfma_f32_16x16x32_bf16(
                    af[mi], bfr[ni], acc[mi][ni], 0, 0, 0);
        __syncthreads();   // all reads done before next staging overwrite
    }

    // epilogue: C/D layout col=lane&15, row=quad*4+reg
    const int rowb = bm * BM + wm + quad * 4;
    const int colb = bn * BN + wn + lr;
#pragma unroll
    for (int ni = 0; ni < 4; ++ni) {
        const int col = colb + ni * 16;
        const float bv = bias[col];
#pragma unroll
        for (int mi = 0; mi < 4; ++mi) {
#pragma unroll
            for (int r = 0; r < 4; ++r) {
                const int row = rowb + mi * 16 + r;
                C[(size_t)row * OUT_DIM + col] = acc[mi][ni][r] + bv;
            }
        }
    }
}

extern "C" void kernel_launch(void* const* d_in, const int* in_sizes, int n_in,
                              void* d_out, int out_size, void* d_ws, size_t ws_size,
                              hipStream_t stream) {
    const float* x     = (const float*)d_in[0];   // [512,4096]
    const float* wf    = (const float*)d_in[1];   // [11008,4096]
    const float* scale = (const float*)d_in[2];   // [11008]
    const float* bias  = (const float*)d_in[3];   // [11008]
    const int*   enc   = (const int*)d_in[4];     // [11008,4096]
    const int*   mask  = (const int*)d_in[5];     // [11008,4096] (bool -> int32 assumed)
    float* out = (float*)d_out;

    short* xq = (short*)d_ws;                       // 512*4096 bf16 = 4 MB
    short* wq = (short*)d_ws + (size_t)T_DIM * IN_DIM;  // 11008*4096 bf16 = 90 MB

    encode_x_kernel<<<(T_DIM * IN_DIM) / (256 * 8), 256, 0, stream>>>(x, xq);
    decode_w_kernel<<<((size_t)OUT_DIM * IN_DIM) / (256 * 8), 256, 0, stream>>>(
        enc, mask, wf, scale, wq);
    dim3 grid(OUT_DIM / BN, T_DIM / BM);   // (86, 4)
    gemm_bt_kernel<<<grid, 256, 0, stream>>>(xq, wq, bias, out);
}